// Round 10
// baseline (2252.921 us; speedup 1.0000x reference)
//
#include <hip/hip_runtime.h>
#include <stdint.h>

// ---------------- problem constants ----------------
#define T_TOK 8192
#define HDIM  2048
#define IDIM  1024
#define NEXP  64
#define KTOP  8
#define TGRP  4
#define TKTOT (T_TOK*KTOP)   // 65536
#define MAXITEMS 12288
#define RSCALE 2.5f

typedef __attribute__((ext_vector_type(8))) short short8;
typedef __attribute__((ext_vector_type(4))) float f32x4;

#define VMCNT(n) asm volatile("s_waitcnt vmcnt(" #n ")" ::: "memory")
#define BARRIER() asm volatile("s_barrier" ::: "memory")

__device__ __forceinline__ float bf2f(uint16_t u) {
    union { unsigned i; float f; } v; v.i = ((unsigned)u) << 16; return v.f;
}
__device__ __forceinline__ uint16_t f2bf(float f) {
    union { float f; unsigned i; } v; v.f = f;
    unsigned r = (v.i + 0x7FFFu + ((v.i >> 16) & 1u)) >> 16;
    return (uint16_t)r;
}
__device__ __forceinline__ void gload_lds16(const void* g, void* l) {
    __builtin_amdgcn_global_load_lds(
        (const __attribute__((address_space(1))) void*)g,
        (__attribute__((address_space(3))) void*)l, 16, 0, 0);
}
__device__ __forceinline__ int imin(int a, int b) { return a < b ? a : b; }

// ---------------- router + grouped topk (unchanged, verified) ----------------
__global__ __launch_bounds__(256) void k_router(
    const float* __restrict__ x, const float* __restrict__ gw,
    const float* __restrict__ ebias,
    int* __restrict__ topk_ids, float* __restrict__ topk_w,
    int* __restrict__ counts)
{
    __shared__ float xs[16][132];
    __shared__ float wsb[64][133];
    __shared__ float sc[16][65];
    __shared__ float su[16][65];
    const int tid = threadIdx.x;
    const int e = tid & 63;
    const int tg = tid >> 6;
    const long tblk = (long)blockIdx.x * 16;

    float acc0 = 0.f, acc1 = 0.f, acc2 = 0.f, acc3 = 0.f;
    for (int ch = 0; ch < 16; ++ch) {
        const int h0 = ch << 7;
        for (int i = tid; i < 512; i += 256) {
            int r = i >> 5, c4 = (i & 31) << 2;
            float4 v = *(const float4*)(x + (tblk + r) * HDIM + h0 + c4);
            *(float4*)&xs[r][c4] = v;
        }
        for (int i = tid; i < 8192; i += 256) {
            int r = i >> 7, c = i & 127;
            wsb[r][c] = gw[(long)r * HDIM + h0 + c];
        }
        __syncthreads();
        #pragma unroll 8
        for (int hh = 0; hh < 128; ++hh) {
            float wv = wsb[e][hh];
            acc0 += xs[tg][hh] * wv;
            acc1 += xs[tg + 4][hh] * wv;
            acc2 += xs[tg + 8][hh] * wv;
            acc3 += xs[tg + 12][hh] * wv;
        }
        __syncthreads();
    }
    const float be = ebias[e];
    {
        float s;
        s = 1.f / (1.f + expf(-acc0)); su[tg][e] = s;      sc[tg][e] = s + be;
        s = 1.f / (1.f + expf(-acc1)); su[tg + 4][e] = s;  sc[tg + 4][e] = s + be;
        s = 1.f / (1.f + expf(-acc2)); su[tg + 8][e] = s;  sc[tg + 8][e] = s + be;
        s = 1.f / (1.f + expf(-acc3)); su[tg + 12][e] = s; sc[tg + 12][e] = s + be;
    }
    __syncthreads();
    if (tid < 16) {
        const int t = tid;
        float gs[8];
        #pragma unroll
        for (int g = 0; g < 8; ++g) {
            float m1 = -1e30f, m2 = -1e30f;
            #pragma unroll
            for (int j = 0; j < 8; ++j) {
                float v = sc[t][g * 8 + j];
                if (v > m1) { m2 = m1; m1 = v; } else if (v > m2) { m2 = v; }
            }
            gs[g] = m1 + m2;
        }
        int selmask = 0;
        #pragma unroll
        for (int it = 0; it < TGRP; ++it) {
            float best = -1e30f; int bg = 0;
            #pragma unroll
            for (int g = 0; g < 8; ++g)
                if (!((selmask >> g) & 1) && gs[g] > best) { best = gs[g]; bg = g; }
            selmask |= (1 << bg);
        }
        unsigned long long chosen = 0ull;
        int ids[KTOP]; float wv[KTOP]; float wsum = 0.f;
        #pragma unroll
        for (int it = 0; it < KTOP; ++it) {
            float best = -1e30f; int bi = 0;
            for (int ee = 0; ee < 64; ++ee) {
                if (((selmask >> (ee >> 3)) & 1) && !((chosen >> ee) & 1ull)) {
                    float v = sc[t][ee];
                    if (v > best) { best = v; bi = ee; }
                }
            }
            chosen |= (1ull << bi);
            ids[it] = bi; wv[it] = su[t][bi]; wsum += wv[it];
        }
        const float inv = 1.f / wsum;
        #pragma unroll
        for (int k = 0; k < KTOP; ++k) {
            topk_ids[(tblk + t) * KTOP + k] = ids[k];
            topk_w[(tblk + t) * KTOP + k] = wv[k] * inv;
            atomicAdd(&counts[ids[k]], 1);
        }
    }
}

// ---------------- offsets + item list (1 wave): 128-row tiles x 16 panels,
// tile-major, + per-XCD chunk bounds.
// qctl: [0..7] q0 cur, [8..15] q0 end, [16..23] q1 cur, [24..31] q1 end
__global__ __launch_bounds__(64) void k_scan5(
    const int* __restrict__ counts, int* offsets, int* cursor,
    int* __restrict__ it_r0, int* __restrict__ it_end,
    int* __restrict__ it_e, int* __restrict__ it_n0,
    int* __restrict__ nitems, int* __restrict__ qctl)
{
    const int e = threadIdx.x;           // 0..63, one wave
    const int c = counts[e];
    int pre = c;
    #pragma unroll
    for (int d = 1; d < 64; d <<= 1) {
        int v = __shfl_up(pre, d, 64);
        if (e >= d) pre += v;
    }
    const int offE = pre - c;
    offsets[e] = offE; cursor[e] = offE;
    const int ntl = (c + 127) >> 7;
    int ipre = ntl;
    #pragma unroll
    for (int d = 1; d < 64; d <<= 1) {
        int v = __shfl_up(ipre, d, 64);
        if (e >= d) ipre += v;
    }
    const int ibase = (ipre - ntl) * 16;
    for (int t = 0; t < ntl; ++t)        // tile-major: 16 panels of a tile adjacent
        for (int p = 0; p < 16; ++p) {
            int idx = ibase + t * 16 + p;
            it_r0[idx] = offE + t * 128;
            it_end[idx] = offE + c;
            it_e[idx] = e;
            it_n0[idx] = p << 7;
        }
    const int totTl = __shfl(ipre, 63, 64);
    const int NI = totTl * 16;
    if (e == 63) *nitems = NI;
    if (e < 8) {
        int s  = (int)(((long)e * NI) / 8);
        int en = (int)(((long)(e + 1) * NI) / 8);
        qctl[e] = s;       qctl[8 + e]  = en;
        qctl[16 + e] = s;  qctl[24 + e] = en;
    }
}

__global__ __launch_bounds__(256) void k_scatter(
    const int* __restrict__ topk_ids, int* cursor,
    int* __restrict__ perm_token, int* __restrict__ slot_of)
{
    int i = blockIdx.x * 256 + threadIdx.x;
    if (i >= TKTOT) return;
    int e = topk_ids[i];
    int pos = atomicAdd(&cursor[e], 1);
    perm_token[pos] = i >> 3;
    slot_of[i] = pos;
}

// ---------------- fp32 -> bf16 elementwise ----------------
__global__ __launch_bounds__(256) void k_cvt_bf16(
    const float* __restrict__ in, uint16_t* __restrict__ outp, long n4)
{
    long i = (long)blockIdx.x * 256 + threadIdx.x;
    if (i >= n4) return;
    float4 v = *(const float4*)(in + i * 4);
    uint64_t pk = (uint64_t)f2bf(v.x) | ((uint64_t)f2bf(v.y) << 16)
                | ((uint64_t)f2bf(v.z) << 32) | ((uint64_t)f2bf(v.w) << 48);
    *(uint64_t*)(outp + i * 4) = pk;
}

// ---------------- tiled transpose + cvt (unchanged) ----------------
template<bool INTER>
__global__ __launch_bounds__(256) void k_transpose2(
    const float* __restrict__ src, uint16_t* __restrict__ dst,
    int R, int C, long sStride, long dStride)
{
    __shared__ float tile[64][65];
    const int c0 = blockIdx.x << 6, r0 = blockIdx.y << 6, s = blockIdx.z;
    const float* S = src + (long)s * sStride;
    uint16_t* D = dst + (long)s * dStride;
    const int lc = (threadIdx.x & 15) << 2;
    const int lr = threadIdx.x >> 4;
    #pragma unroll
    for (int p = 0; p < 4; ++p) {
        int y = lr + p * 16;
        float4 v = *(const float4*)(S + (long)(r0 + y) * C + c0 + lc);
        tile[y][lc] = v.x; tile[y][lc + 1] = v.y;
        tile[y][lc + 2] = v.z; tile[y][lc + 3] = v.w;
    }
    __syncthreads();
    const int wc = threadIdx.x >> 3;
    const int wx = (threadIdx.x & 7) << 3;
    #pragma unroll
    for (int p = 0; p < 2; ++p) {
        int c = wc + p * 32;
        short8 v;
        #pragma unroll
        for (int j = 0; j < 8; ++j) v[j] = (short)f2bf(tile[wx + j][c]);
        int cg = c0 + c;
        int rd = INTER ? (((cg & (IDIM - 1)) << 1) + (cg >> 10)) : cg;
        *(short8*)(D + (long)rd * R + r0 + wx) = v;
    }
}

// ---------------- MFMA GEMM v10: 128x128, 4 waves, 3x16KB buffers ->
// 48KB LDS -> 3 blocks/CU (3 waves/SIMD) so cross-block overlap hides stalls.
// Per K-tile: [VMCNT(4/0); BAR; 8 ds_read + 4 gload(kt+2 -> buf read at kt-1);
// BAR; setprio + 16 MFMA]. v9 per-XCD tile-major queues; verified swizzle.
template<bool GATEUP, bool ROUTED>
__global__ __launch_bounds__(256, 3) void k_gemm10(
    const uint16_t* __restrict__ A, const uint16_t* __restrict__ Bw,
    void* __restrict__ OutP,
    const int* __restrict__ perm_token,
    const int* __restrict__ it_r0, const int* __restrict__ it_end,
    const int* __restrict__ it_e, const int* __restrict__ it_n0,
    const int* __restrict__ nitems, int* __restrict__ qcur,
    int Kd, long expStride)
{
    __shared__ char ldsb[3 * 16384];   // buf: A [0,8K), B [8K,16K)
    __shared__ int s_item;
    const int tid = threadIdx.x, lane = tid & 63, wid = tid >> 6;  // 4 waves
    const int wm = wid >> 1, wn = wid & 1;          // 2M x 2N (64x64 per wave)

    const int rchunk = lane >> 2;                                   // 0..15
    const int swzS = ((lane & 3) ^ ((lane >> 3) & 3)) << 3;         // src k-elem off
    const int swzR = ((lane >> 4) ^ ((lane >> 1) & 3)) << 4;
    const int aoff = (wm * 64 + (lane & 15)) * 64 + swzR;
    const int boff = (wn * 64 + (lane & 15)) * 64 + swzR;
    const int dst0 = (wid * 2) * 1024;        // rows wid*32..+15
    const int dst1 = (wid * 2 + 1) * 1024;    // rows wid*32+16..+31

    const int nKt = Kd >> 5;
    const int xcd = (int)(blockIdx.x & 7);
    const int myEnd = ROUTED ? qcur[8 + xcd] : 0;
    int* myCur = qcur + xcd;

    for (;;) {
        int row0, end, n0; long eoff;
        if (ROUTED) {
            __syncthreads();                  // full fence between items
            if (tid == 0) s_item = atomicAdd(myCur, 1);
            __syncthreads();
            const int it = s_item;
            if (it >= myEnd) break;
            row0 = it_r0[it]; end = it_end[it]; n0 = it_n0[it];
            eoff = (long)it_e[it] * expStride;
        } else {
            row0 = (int)(blockIdx.x >> 4) << 7;
            end = row0 + 128;
            n0 = (int)(blockIdx.x & 15) << 7;
            eoff = 0;
        }

        const uint16_t *pa0, *pa1, *pb0, *pb1;
        {
            int r0l = wid * 32 + rchunk;
            int r1l = r0l + 16;
            int ra0 = row0 + r0l, ra1 = row0 + r1l;
            if (ROUTED) { ra0 = imin(ra0, end - 1); ra1 = imin(ra1, end - 1); }
            long ga0 = (GATEUP && ROUTED) ? (long)perm_token[ra0] : (long)ra0;
            long ga1 = (GATEUP && ROUTED) ? (long)perm_token[ra1] : (long)ra1;
            pa0 = A + ga0 * Kd + swzS;
            pa1 = A + ga1 * Kd + swzS;
            pb0 = Bw + eoff + (long)(n0 + r0l) * Kd + swzS;
            pb1 = Bw + eoff + (long)(n0 + r1l) * Kd + swzS;
        }

        f32x4 acc[4][4];
        #pragma unroll
        for (int f = 0; f < 4; ++f)
            #pragma unroll
            for (int g = 0; g < 4; ++g) { f32x4 z = {0.f,0.f,0.f,0.f}; acc[f][g] = z; }

        // prologue: stage kt=0 -> buf0, kt=1 -> buf1
        gload_lds16(pa0, ldsb + dst0);
        gload_lds16(pa1, ldsb + dst1);
        gload_lds16(pb0, ldsb + 8192 + dst0);
        gload_lds16(pb1, ldsb + 8192 + dst1);
        gload_lds16(pa0 + 32, ldsb + 16384 + dst0);
        gload_lds16(pa1 + 32, ldsb + 16384 + dst1);
        gload_lds16(pb0 + 32, ldsb + 16384 + 8192 + dst0);
        gload_lds16(pb1 + 32, ldsb + 16384 + 8192 + dst1);

        int cur = 0, stg = 2;   // stg = (cur+2)%3 : buffer read at kt-1
        for (int kt = 0; kt < nKt; ++kt) {
            if (kt + 1 < nKt) VMCNT(4);   // kt's 4 loads landed; kt+1 in flight
            else              VMCNT(0);
            BARRIER();                     // all waves' kt stage landed;
                                           // all waves' kt-1 MFMAs done -> stg free
            const char* bb = ldsb + cur * 16384;
            char* bs = ldsb + stg * 16384;
            short8 fa0 = *(const short8*)(bb + aoff);
            short8 fa1 = *(const short8*)(bb + aoff + 1024);
            short8 fa2 = *(const short8*)(bb + aoff + 2048);
            short8 fa3 = *(const short8*)(bb + aoff + 3072);
            short8 fb0 = *(const short8*)(bb + 8192 + boff);
            short8 fb1 = *(const short8*)(bb + 8192 + boff + 1024);
            short8 fb2 = *(const short8*)(bb + 8192 + boff + 2048);
            short8 fb3 = *(const short8*)(bb + 8192 + boff + 3072);
            if (kt + 2 < nKt) {
                gload_lds16(pa0 + ((kt + 2) << 5), bs + dst0);
                gload_lds16(pa1 + ((kt + 2) << 5), bs + dst1);
                gload_lds16(pb0 + ((kt + 2) << 5), bs + 8192 + dst0);
                gload_lds16(pb1 + ((kt + 2) << 5), bs + 8192 + dst1);
            }
            BARRIER();
            __builtin_amdgcn_s_setprio(1);
            acc[0][0] = __builtin_amdgcn_mfma_f32_16x16x32_bf16(fa0, fb0, acc[0][0], 0, 0, 0);
            acc[0][1] = __builtin_amdgcn_mfma_f32_16x16x32_bf16(fa0, fb1, acc[0][1], 0, 0, 0);
            acc[0][2] = __builtin_amdgcn_mfma_f32_16x16x32_bf16(fa0, fb2, acc[0][2], 0, 0, 0);
            acc[0][3] = __builtin_amdgcn_mfma_f32_16x16x32_bf16(fa0, fb3, acc[0][3], 0, 0, 0);
            acc[1][0] = __builtin_amdgcn_mfma_f32_16x16x32_bf16(fa1, fb0, acc[1][0], 0, 0, 0);
            acc[1][1] = __builtin_amdgcn_mfma_f32_16x16x32_bf16(fa1, fb1, acc[1][1], 0, 0, 0);
            acc[1][2] = __builtin_amdgcn_mfma_f32_16x16x32_bf16(fa1, fb2, acc[1][2], 0, 0, 0);
            acc[1][3] = __builtin_amdgcn_mfma_f32_16x16x32_bf16(fa1, fb3, acc[1][3], 0, 0, 0);
            acc[2][0] = __builtin_amdgcn_mfma_f32_16x16x32_bf16(fa2, fb0, acc[2][0], 0, 0, 0);
            acc[2][1] = __builtin_amdgcn_mfma_f32_16x16x32_bf16(fa2, fb1, acc[2][1], 0, 0, 0);
            acc[2][2] = __builtin_amdgcn_mfma_f32_16x16x32_bf16(fa2, fb2, acc[2][2], 0, 0, 0);
            acc[2][3] = __builtin_amdgcn_mfma_f32_16x16x32_bf16(fa2, fb3, acc[2][3], 0, 0, 0);
            acc[3][0] = __builtin_amdgcn_mfma_f32_16x16x32_bf16(fa3, fb0, acc[3][0], 0, 0, 0);
            acc[3][1] = __builtin_amdgcn_mfma_f32_16x16x32_bf16(fa3, fb1, acc[3][1], 0, 0, 0);
            acc[3][2] = __builtin_amdgcn_mfma_f32_16x16x32_bf16(fa3, fb2, acc[3][2], 0, 0, 0);
            acc[3][3] = __builtin_amdgcn_mfma_f32_16x16x32_bf16(fa3, fb3, acc[3][3], 0, 0, 0);
            __builtin_amdgcn_s_setprio(0);
            cur = (cur == 2) ? 0 : cur + 1;
            stg = (stg == 2) ? 0 : stg + 1;
        }

        // epilogue
        const int colb = n0 + wn * 64 + (lane & 15);
        const int rowbase = row0 + wm * 64 + ((lane >> 4) << 2);
        if (GATEUP) {
            uint16_t* Oact = (uint16_t*)OutP;
            const bool evenl = ((lane & 1) == 0);
            #pragma unroll
            for (int f = 0; f < 4; ++f)
                #pragma unroll
                for (int g = 0; g < 4; ++g) {
                    f32x4 v = acc[f][g];
                    #pragma unroll
                    for (int r = 0; r < 4; ++r) {
                        float gg = v[r];
                        float uu = __shfl_xor(gg, 1, 64);
                        int row = rowbase + f * 16 + r;
                        if (evenl && (!ROUTED || row < end)) {
                            int jcol = (colb + g * 16) >> 1;
                            float sg = gg / (1.f + __expf(-gg));
                            Oact[(long)row * IDIM + jcol] = f2bf(sg * uu);
                        }
                    }
                }
        } else if (ROUTED) {
            uint16_t* Y = (uint16_t*)OutP;
            #pragma unroll
            for (int f = 0; f < 4; ++f)
                #pragma unroll
                for (int g = 0; g < 4; ++g) {
                    f32x4 v = acc[f][g];
                    #pragma unroll
                    for (int r = 0; r < 4; ++r) {
                        int row = rowbase + f * 16 + r;
                        if (row < end)
                            Y[(long)row * HDIM + colb + g * 16] = f2bf(v[r]);
                    }
                }
        } else {
            float* O = (float*)OutP;
            #pragma unroll
            for (int f = 0; f < 4; ++f)
                #pragma unroll
                for (int g = 0; g < 4; ++g) {
                    f32x4 v = acc[f][g];
                    #pragma unroll
                    for (int r = 0; r < 4; ++r) {
                        int row = rowbase + f * 16 + r;
                        O[(long)row * HDIM + colb + g * 16] = v[r];
                    }
                }
        }
        if (!ROUTED) break;
    }
}

// ---------------- combine: out = shared + 2.5 * sum_k w_k * y[slot_k] ----------------
__global__ __launch_bounds__(256) void k_combine(
    float* __restrict__ out, const uint16_t* __restrict__ ybuf,
    const int* __restrict__ slot_of, const float* __restrict__ topk_w)
{
    __shared__ int sl[KTOP];
    __shared__ float sw[KTOP];
    const int t = blockIdx.x, tid = threadIdx.x;
    if (tid < KTOP) {
        sl[tid] = slot_of[t * KTOP + tid];
        sw[tid] = topk_w[t * KTOP + tid] * RSCALE;
    }
    __syncthreads();
    const int h0 = tid << 3;
    float* orow = out + (long)t * HDIM + h0;
    float4 v0 = *(const float4*)(orow);
    float4 v1 = *(const float4*)(orow + 4);
    float a[8] = { v0.x, v0.y, v0.z, v0.w, v1.x, v1.y, v1.z, v1.w };
    #pragma unroll
    for (int k = 0; k < KTOP; ++k) {
        const uint16_t* yr = ybuf + (long)sl[k] * HDIM + h0;
        short8 y = *(const short8*)yr;
        float w = sw[k];
        #pragma unroll
        for (int j = 0; j < 8; ++j)
            a[j] += w * bf2f((uint16_t)y[j]);
    }
    v0.x = a[0]; v0.y = a[1]; v0.z = a[2]; v0.w = a[3];
    v1.x = a[4]; v1.y = a[5]; v1.z = a[6]; v1.w = a[7];
    *(float4*)(orow) = v0;
    *(float4*)(orow + 4) = v1;
}

// ---------------- launch ----------------
extern "C" void kernel_launch(void* const* d_in, const int* in_sizes, int n_in,
                              void* d_out, int out_size, void* d_ws, size_t ws_size,
                              hipStream_t stream)
{
    const float* x  = (const float*)d_in[0];
    const float* gw = (const float*)d_in[1];
    const float* eb = (const float*)d_in[2];
    const float* w1 = (const float*)d_in[3];
    const float* w2 = (const float*)d_in[4];
    const float* s1 = (const float*)d_in[5];
    const float* s2 = (const float*)d_in[6];
    float* out = (float*)d_out;
    char* ws = (char*)d_ws;

    size_t off = 0;
    auto take = [&](size_t b) { size_t r = off; off += (b + 255) & ~(size_t)255; return r; };
    const size_t oXBF = take((size_t)T_TOK * HDIM * 2);
    const size_t oACT = take((size_t)TKTOT * IDIM * 2);
    const size_t oASH = take((size_t)T_TOK * IDIM * 2);
    const size_t oW1T = take((size_t)NEXP * 2048 * 2048 * 2);  // aliased as ybuf after gate_up
    const size_t oW2T = take((size_t)NEXP * 2048 * 1024 * 2);
    const size_t oS1T = take((size_t)2048 * 2048 * 2);
    const size_t oS2T = take((size_t)2048 * 1024 * 2);
    const size_t oTKI = take((size_t)TKTOT * 4);
    const size_t oTKW = take((size_t)TKTOT * 4);
    const size_t oSLT = take((size_t)TKTOT * 4);
    const size_t oPRM = take((size_t)TKTOT * 4);
    const size_t oCTL = take(1024);     // [0..63]=counts, [64..95]=qctl
    const size_t oOFS = take(256);
    const size_t oCUR = take(256);
    const size_t oNT  = take(256);
    const size_t oIR  = take(MAXITEMS * 4);
    const size_t oIE  = take(MAXITEMS * 4);
    const size_t oIX  = take(MAXITEMS * 4);
    const size_t oIN  = take(MAXITEMS * 4);
    (void)ws_size; (void)in_sizes; (void)n_in; (void)out_size;

    uint16_t* xbf  = (uint16_t*)(ws + oXBF);
    uint16_t* act  = (uint16_t*)(ws + oACT);
    uint16_t* ash  = (uint16_t*)(ws + oASH);
    uint16_t* w1t  = (uint16_t*)(ws + oW1T);
    uint16_t* ybuf = (uint16_t*)(ws + oW1T);
    uint16_t* w2t  = (uint16_t*)(ws + oW2T);
    uint16_t* s1t  = (uint16_t*)(ws + oS1T);
    uint16_t* s2t  = (uint16_t*)(ws + oS2T);
    int*   tki  = (int*)(ws + oTKI);
    float* tkw  = (float*)(ws + oTKW);
    int*   slot = (int*)(ws + oSLT);
    int*   prm  = (int*)(ws + oPRM);
    int*   ctl  = (int*)(ws + oCTL);
    int*   ofs  = (int*)(ws + oOFS);
    int*   cur  = (int*)(ws + oCUR);
    int*   nt   = (int*)(ws + oNT);
    int*   ir0  = (int*)(ws + oIR);
    int*   iend = (int*)(ws + oIE);
    int*   ie   = (int*)(ws + oIX);
    int*   in0  = (int*)(ws + oIN);
    int*   qctl = ctl + 64;

    hipMemsetAsync(ws + oCTL, 0, 1024, stream);

    k_router<<<T_TOK / 16, 256, 0, stream>>>(x, gw, eb, tki, tkw, ctl);
    k_scan5<<<1, 64, 0, stream>>>(ctl, ofs, cur, ir0, iend, ie, in0, nt, qctl);
    k_scatter<<<TKTOT / 256, 256, 0, stream>>>(tki, cur, prm, slot);

    k_cvt_bf16<<<(T_TOK * HDIM / 4 + 255) / 256, 256, 0, stream>>>(x, xbf, (long)T_TOK * HDIM / 4);
    k_transpose2<true ><<<dim3(32, 32, NEXP), 256, 0, stream>>>(w1, w1t, 2048, 2048,
        (long)2048 * 2048, (long)2048 * 2048);
    k_transpose2<false><<<dim3(32, 16, NEXP), 256, 0, stream>>>(w2, w2t, 1024, 2048,
        (long)1024 * 2048, (long)2048 * 1024);
    k_transpose2<true ><<<dim3(32, 32, 1), 256, 0, stream>>>(s1, s1t, 2048, 2048, 0, 0);
    k_transpose2<false><<<dim3(32, 16, 1), 256, 0, stream>>>(s2, s2t, 1024, 2048, 0, 0);

    // shared expert gate_up (+silu*mul) -> ash   (64 Mtiles x 16 panels)
    k_gemm10<true, false><<<dim3(1024), 256, 0, stream>>>(
        xbf, s1t, ash, nullptr, nullptr, nullptr, nullptr, nullptr, nullptr, qctl, 2048, 0);
    // routed gate_up (+silu*mul) -> act   (per-XCD queues q0; 3 blocks/CU)
    k_gemm10<true, true><<<dim3(768), 256, 0, stream>>>(
        xbf, w1t, act, prm, ir0, iend, ie, in0, nt, qctl, 2048, (long)2048 * 2048);
    // shared down -> d_out (f32)
    k_gemm10<false, false><<<dim3(1024), 256, 0, stream>>>(
        ash, s2t, out, nullptr, nullptr, nullptr, nullptr, nullptr, nullptr, qctl, 1024, 0);
    // routed down -> ybuf (bf16, aliases w1t; per-XCD queues q1)
    k_gemm10<false, true><<<dim3(768), 256, 0, stream>>>(
        act, w2t, ybuf, nullptr, ir0, iend, ie, in0, nt, qctl + 16, 1024, (long)2048 * 1024);

    k_combine<<<T_TOK, 256, 0, stream>>>(out, ybuf, slot, tkw);
}

// Round 11
// 2113.009 us; speedup vs baseline: 1.0662x; 1.0662x over previous
//
#include <hip/hip_runtime.h>
#include <stdint.h>

// ---------------- problem constants ----------------
#define T_TOK 8192
#define HDIM  2048
#define IDIM  1024
#define NEXP  64
#define KTOP  8
#define TGRP  4
#define TKTOT (T_TOK*KTOP)   // 65536
#define NSLOT (TKTOT + T_TOK) // routed slots + shared rows
#define MAXITEMS 4096
#define RSCALE 2.5f

typedef __attribute__((ext_vector_type(8))) short short8;
typedef __attribute__((ext_vector_type(4))) float f32x4;

#define VMCNT(n) asm volatile("s_waitcnt vmcnt(" #n ")" ::: "memory")
#define BARRIER() asm volatile("s_barrier" ::: "memory")

__device__ __forceinline__ float bf2f(uint16_t u) {
    union { unsigned i; float f; } v; v.i = ((unsigned)u) << 16; return v.f;
}
__device__ __forceinline__ uint16_t f2bf(float f) {
    union { float f; unsigned i; } v; v.f = f;
    unsigned r = (v.i + 0x7FFFu + ((v.i >> 16) & 1u)) >> 16;
    return (uint16_t)r;
}
__device__ __forceinline__ void gload_lds16(const void* g, void* l) {
    __builtin_amdgcn_global_load_lds(
        (const __attribute__((address_space(1))) void*)g,
        (__attribute__((address_space(3))) void*)l, 16, 0, 0);
}
__device__ __forceinline__ int imin(int a, int b) { return a < b ? a : b; }

// ---------------- router + grouped topk + fused x->bf16 ----------------
__global__ __launch_bounds__(256) void k_router(
    const float* __restrict__ x, const float* __restrict__ gw,
    const float* __restrict__ ebias,
    int* __restrict__ topk_ids, float* __restrict__ topk_w,
    int* __restrict__ counts, uint16_t* __restrict__ xbf)
{
    __shared__ float xs[16][132];
    __shared__ float wsb[64][133];
    __shared__ float sc[16][65];
    __shared__ float su[16][65];
    const int tid = threadIdx.x;
    const int e = tid & 63;
    const int tg = tid >> 6;
    const long tblk = (long)blockIdx.x * 16;

    float acc0 = 0.f, acc1 = 0.f, acc2 = 0.f, acc3 = 0.f;
    for (int ch = 0; ch < 16; ++ch) {
        const int h0 = ch << 7;
        for (int i = tid; i < 512; i += 256) {
            int r = i >> 5, c4 = (i & 31) << 2;
            float4 v = *(const float4*)(x + (tblk + r) * HDIM + h0 + c4);
            *(float4*)&xs[r][c4] = v;
            uint64_t pk = (uint64_t)f2bf(v.x) | ((uint64_t)f2bf(v.y) << 16)
                        | ((uint64_t)f2bf(v.z) << 32) | ((uint64_t)f2bf(v.w) << 48);
            *(uint64_t*)(xbf + (tblk + r) * HDIM + h0 + c4) = pk;
        }
        for (int i = tid; i < 8192; i += 256) {
            int r = i >> 7, c = i & 127;
            wsb[r][c] = gw[(long)r * HDIM + h0 + c];
        }
        __syncthreads();
        #pragma unroll 8
        for (int hh = 0; hh < 128; ++hh) {
            float wv = wsb[e][hh];
            acc0 += xs[tg][hh] * wv;
            acc1 += xs[tg + 4][hh] * wv;
            acc2 += xs[tg + 8][hh] * wv;
            acc3 += xs[tg + 12][hh] * wv;
        }
        __syncthreads();
    }
    const float be = ebias[e];
    {
        float s;
        s = 1.f / (1.f + expf(-acc0)); su[tg][e] = s;      sc[tg][e] = s + be;
        s = 1.f / (1.f + expf(-acc1)); su[tg + 4][e] = s;  sc[tg + 4][e] = s + be;
        s = 1.f / (1.f + expf(-acc2)); su[tg + 8][e] = s;  sc[tg + 8][e] = s + be;
        s = 1.f / (1.f + expf(-acc3)); su[tg + 12][e] = s; sc[tg + 12][e] = s + be;
    }
    __syncthreads();
    if (tid < 16) {
        const int t = tid;
        float gs[8];
        #pragma unroll
        for (int g = 0; g < 8; ++g) {
            float m1 = -1e30f, m2 = -1e30f;
            #pragma unroll
            for (int j = 0; j < 8; ++j) {
                float v = sc[t][g * 8 + j];
                if (v > m1) { m2 = m1; m1 = v; } else if (v > m2) { m2 = v; }
            }
            gs[g] = m1 + m2;
        }
        int selmask = 0;
        #pragma unroll
        for (int it = 0; it < TGRP; ++it) {
            float best = -1e30f; int bg = 0;
            #pragma unroll
            for (int g = 0; g < 8; ++g)
                if (!((selmask >> g) & 1) && gs[g] > best) { best = gs[g]; bg = g; }
            selmask |= (1 << bg);
        }
        unsigned long long chosen = 0ull;
        int ids[KTOP]; float wv[KTOP]; float wsum = 0.f;
        #pragma unroll
        for (int it = 0; it < KTOP; ++it) {
            float best = -1e30f; int bi = 0;
            for (int ee = 0; ee < 64; ++ee) {
                if (((selmask >> (ee >> 3)) & 1) && !((chosen >> ee) & 1ull)) {
                    float v = sc[t][ee];
                    if (v > best) { best = v; bi = ee; }
                }
            }
            chosen |= (1ull << bi);
            ids[it] = bi; wv[it] = su[t][bi]; wsum += wv[it];
        }
        const float inv = 1.f / wsum;
        #pragma unroll
        for (int k = 0; k < KTOP; ++k) {
            topk_ids[(tblk + t) * KTOP + k] = ids[k];
            topk_w[(tblk + t) * KTOP + k] = wv[k] * inv;
            atomicAdd(&counts[ids[k]], 1);
        }
    }
}

// ---------------- offsets + item list (1 wave): 256-row tiles x 8 panels,
// tile-major; shared expert appended as expert 64 (rows TKTOT..TKTOT+8192).
// qctl: [0..7] q0 cur, [8..15] q0 end, [16..23] q1 cur, [24..31] q1 end
__global__ __launch_bounds__(64) void k_scan6(
    const int* __restrict__ counts, int* offsets, int* cursor,
    int* __restrict__ it_r0, int* __restrict__ it_end,
    int* __restrict__ it_e, int* __restrict__ it_n0,
    int* __restrict__ nitems, int* __restrict__ qctl)
{
    const int e = threadIdx.x;           // 0..63, one wave
    const int c = counts[e];
    int pre = c;
    #pragma unroll
    for (int d = 1; d < 64; d <<= 1) {
        int v = __shfl_up(pre, d, 64);
        if (e >= d) pre += v;
    }
    const int offE = pre - c;
    offsets[e] = offE; cursor[e] = offE;
    const int ntl = (c + 255) >> 8;
    int ipre = ntl;
    #pragma unroll
    for (int d = 1; d < 64; d <<= 1) {
        int v = __shfl_up(ipre, d, 64);
        if (e >= d) ipre += v;
    }
    const int ibase = (ipre - ntl) * 8;
    for (int t = 0; t < ntl; ++t)        // tile-major: 8 panels of a tile adjacent
        for (int p = 0; p < 8; ++p) {
            int idx = ibase + t * 8 + p;
            it_r0[idx] = offE + t * 256;
            it_end[idx] = offE + c;
            it_e[idx] = e;
            it_n0[idx] = p << 8;
        }
    const int totTl = __shfl(ipre, 63, 64);
    int NI = totTl * 8;
    // shared expert = expert 64: 32 tiles (8192 rows) x 8 panels
    if (e < 32) {
        for (int p = 0; p < 8; ++p) {
            int idx = NI + e * 8 + p;
            it_r0[idx] = TKTOT + e * 256;
            it_end[idx] = TKTOT + T_TOK;
            it_e[idx] = 64;
            it_n0[idx] = p << 8;
        }
    }
    NI += 256;
    if (e == 63) *nitems = NI;
    if (e < 8) {
        int s  = (int)(((long)e * NI) / 8);
        int en = (int)(((long)(e + 1) * NI) / 8);
        qctl[e] = s;       qctl[8 + e]  = en;
        qctl[16 + e] = s;  qctl[24 + e] = en;
    }
}

// scatter routed slots; extend perm with identity for shared rows
__global__ __launch_bounds__(256) void k_scatter(
    const int* __restrict__ topk_ids, int* cursor,
    int* __restrict__ perm_token, int* __restrict__ slot_of)
{
    int i = blockIdx.x * 256 + threadIdx.x;
    if (i < TKTOT) {
        int e = topk_ids[i];
        int pos = atomicAdd(&cursor[e], 1);
        perm_token[pos] = i >> 3;
        slot_of[i] = pos;
    } else if (i < NSLOT) {
        perm_token[i] = i - TKTOT;
    }
}

// ---------------- tiled transpose + cvt; z==NEXP pulls from src2 ----------------
template<bool INTER>
__global__ __launch_bounds__(256) void k_transpose3(
    const float* __restrict__ src, const float* __restrict__ src2,
    uint16_t* __restrict__ dst,
    int R, int C, long sStride, long dStride)
{
    __shared__ float tile[64][65];
    const int c0 = blockIdx.x << 6, r0 = blockIdx.y << 6, s = blockIdx.z;
    const float* S = (s == NEXP) ? src2 : (src + (long)s * sStride);
    uint16_t* D = dst + (long)s * dStride;
    const int lc = (threadIdx.x & 15) << 2;
    const int lr = threadIdx.x >> 4;
    #pragma unroll
    for (int p = 0; p < 4; ++p) {
        int y = lr + p * 16;
        float4 v = *(const float4*)(S + (long)(r0 + y) * C + c0 + lc);
        tile[y][lc] = v.x; tile[y][lc + 1] = v.y;
        tile[y][lc + 2] = v.z; tile[y][lc + 3] = v.w;
    }
    __syncthreads();
    const int wc = threadIdx.x >> 3;
    const int wx = (threadIdx.x & 7) << 3;
    #pragma unroll
    for (int p = 0; p < 2; ++p) {
        int c = wc + p * 32;
        short8 v;
        #pragma unroll
        for (int j = 0; j < 8; ++j) v[j] = (short)f2bf(tile[wx + j][c]);
        int cg = c0 + c;
        int rd = INTER ? (((cg & (IDIM - 1)) << 1) + (cg >> 10)) : cg;
        *(short8*)(D + (long)rd * R + r0 + wx) = v;
    }
}

// ---------------- MFMA GEMM v11: v9 engine verbatim (256x256, 8 waves, 4-buf
// BK=32, canonical phases, tail-correct vmcnt, per-XCD tile-major queues).
template<bool GATEUP>
__global__ __launch_bounds__(512, 2) void k_gemm11(
    const uint16_t* __restrict__ A, const uint16_t* __restrict__ Bw,
    void* __restrict__ OutP,
    const int* __restrict__ perm_token,
    const int* __restrict__ it_r0, const int* __restrict__ it_end,
    const int* __restrict__ it_e, const int* __restrict__ it_n0,
    int* __restrict__ qcur,
    int Kd, long expStride)
{
    __shared__ char ldsb[4 * 32768];
    __shared__ int s_item;
    const int tid = threadIdx.x, lane = tid & 63, wid = tid >> 6;
    const int wm = wid >> 2, wn = wid & 3;          // 2M x 4N wave grid

    const int rchunk = lane >> 2;                                   // 0..15
    const int swzS = ((lane & 3) ^ ((lane >> 3) & 3)) << 3;         // src k-elem off
    const int swzR = ((lane >> 4) ^ ((lane >> 1) & 3)) << 4;
    const int aoff = (wm * 128 + (lane & 15)) * 64 + swzR;
    const int boff = (wn * 64 + (lane & 15)) * 64 + swzR;
    const int dstA0 = (wid * 2) * 1024;
    const int dstA1 = (wid * 2 + 1) * 1024;

    const int nKt = Kd >> 5;
    const int xcd = (int)(blockIdx.x & 7);
    const int myEnd = qcur[8 + xcd];
    int* myCur = qcur + xcd;

    for (;;) {
        __syncthreads();                  // full fence between items
        if (tid == 0) s_item = atomicAdd(myCur, 1);
        __syncthreads();
        const int it = s_item;
        if (it >= myEnd) break;
        const int row0 = it_r0[it], end = it_end[it], n0 = it_n0[it];
        const long eoff = (long)it_e[it] * expStride;

        // staging pointers: chunk c covers rows wid*32 + c*16 + rchunk
        const uint16_t *pa0, *pa1, *pb0, *pb1;
        {
            int r0l = wid * 32 + rchunk;
            int r1l = wid * 32 + 16 + rchunk;
            int ra0 = imin(row0 + r0l, end - 1);
            int ra1 = imin(row0 + r1l, end - 1);
            long ga0 = GATEUP ? (long)perm_token[ra0] : (long)ra0;
            long ga1 = GATEUP ? (long)perm_token[ra1] : (long)ra1;
            pa0 = A + ga0 * Kd + swzS;
            pa1 = A + ga1 * Kd + swzS;
            pb0 = Bw + eoff + (long)(n0 + r0l) * Kd + swzS;
            pb1 = Bw + eoff + (long)(n0 + r1l) * Kd + swzS;
        }

        f32x4 acc[8][4];
        #pragma unroll
        for (int f = 0; f < 8; ++f)
            #pragma unroll
            for (int g = 0; g < 4; ++g) { f32x4 z = {0.f,0.f,0.f,0.f}; acc[f][g] = z; }

        // prologue: stage K-tiles 0,1,2 (4 loads each per wave)
        #pragma unroll
        for (int j = 0; j < 3; ++j) {
            char* bb = ldsb + j * 32768;
            gload_lds16(pa0 + (j << 5), bb + dstA0);
            gload_lds16(pa1 + (j << 5), bb + dstA1);
            gload_lds16(pb0 + (j << 5), bb + 16384 + dstA0);
            gload_lds16(pb1 + (j << 5), bb + 16384 + dstA1);
        }

        for (int kt = 0; kt < nKt; ++kt) {
            const char* bb = ldsb + (kt & 3) * 32768;
            char* bs = ldsb + ((kt + 3) & 3) * 32768;
            const bool st = (kt + 3) < nKt;

            if (kt + 2 < nKt)      VMCNT(8);   // kt landed; kt+1,kt+2 in flight
            else if (kt + 1 < nKt) VMCNT(4);
            else                   VMCNT(0);
            BARRIER();                          // ... on every wave

            // ---- phase 0: reads fA0-3 + fB0-3, stage A(kt+3) ----
            short8 fa0 = *(const short8*)(bb + aoff);
            short8 fa1 = *(const short8*)(bb + aoff + 1024);
            short8 fa2 = *(const short8*)(bb + aoff + 2048);
            short8 fa3 = *(const short8*)(bb + aoff + 3072);
            short8 fb0 = *(const short8*)(bb + 16384 + boff);
            short8 fb1 = *(const short8*)(bb + 16384 + boff + 1024);
            short8 fb2 = *(const short8*)(bb + 16384 + boff + 2048);
            short8 fb3 = *(const short8*)(bb + 16384 + boff + 3072);
            if (st) {
                gload_lds16(pa0 + ((kt + 3) << 5), bs + dstA0);
                gload_lds16(pa1 + ((kt + 3) << 5), bs + dstA1);
            }
            BARRIER();
            __builtin_amdgcn_s_setprio(1);
            acc[0][0] = __builtin_amdgcn_mfma_f32_16x16x32_bf16(fa0, fb0, acc[0][0], 0, 0, 0);
            acc[0][1] = __builtin_amdgcn_mfma_f32_16x16x32_bf16(fa0, fb1, acc[0][1], 0, 0, 0);
            acc[0][2] = __builtin_amdgcn_mfma_f32_16x16x32_bf16(fa0, fb2, acc[0][2], 0, 0, 0);
            acc[0][3] = __builtin_amdgcn_mfma_f32_16x16x32_bf16(fa0, fb3, acc[0][3], 0, 0, 0);
            acc[1][0] = __builtin_amdgcn_mfma_f32_16x16x32_bf16(fa1, fb0, acc[1][0], 0, 0, 0);
            acc[1][1] = __builtin_amdgcn_mfma_f32_16x16x32_bf16(fa1, fb1, acc[1][1], 0, 0, 0);
            acc[1][2] = __builtin_amdgcn_mfma_f32_16x16x32_bf16(fa1, fb2, acc[1][2], 0, 0, 0);
            acc[1][3] = __builtin_amdgcn_mfma_f32_16x16x32_bf16(fa1, fb3, acc[1][3], 0, 0, 0);
            acc[2][0] = __builtin_amdgcn_mfma_f32_16x16x32_bf16(fa2, fb0, acc[2][0], 0, 0, 0);
            acc[2][1] = __builtin_amdgcn_mfma_f32_16x16x32_bf16(fa2, fb1, acc[2][1], 0, 0, 0);
            acc[2][2] = __builtin_amdgcn_mfma_f32_16x16x32_bf16(fa2, fb2, acc[2][2], 0, 0, 0);
            acc[2][3] = __builtin_amdgcn_mfma_f32_16x16x32_bf16(fa2, fb3, acc[2][3], 0, 0, 0);
            acc[3][0] = __builtin_amdgcn_mfma_f32_16x16x32_bf16(fa3, fb0, acc[3][0], 0, 0, 0);
            acc[3][1] = __builtin_amdgcn_mfma_f32_16x16x32_bf16(fa3, fb1, acc[3][1], 0, 0, 0);
            acc[3][2] = __builtin_amdgcn_mfma_f32_16x16x32_bf16(fa3, fb2, acc[3][2], 0, 0, 0);
            acc[3][3] = __builtin_amdgcn_mfma_f32_16x16x32_bf16(fa3, fb3, acc[3][3], 0, 0, 0);
            __builtin_amdgcn_s_setprio(0);

            // ---- phase 1: reads fA4-7, stage B(kt+3) ----
            short8 fa4 = *(const short8*)(bb + aoff + 4096);
            short8 fa5 = *(const short8*)(bb + aoff + 5120);
            short8 fa6 = *(const short8*)(bb + aoff + 6144);
            short8 fa7 = *(const short8*)(bb + aoff + 7168);
            if (st) {
                gload_lds16(pb0 + ((kt + 3) << 5), bs + 16384 + dstA0);
                gload_lds16(pb1 + ((kt + 3) << 5), bs + 16384 + dstA1);
            }
            BARRIER();
            __builtin_amdgcn_s_setprio(1);
            acc[4][0] = __builtin_amdgcn_mfma_f32_16x16x32_bf16(fa4, fb0, acc[4][0], 0, 0, 0);
            acc[4][1] = __builtin_amdgcn_mfma_f32_16x16x32_bf16(fa4, fb1, acc[4][1], 0, 0, 0);
            acc[4][2] = __builtin_amdgcn_mfma_f32_16x16x32_bf16(fa4, fb2, acc[4][2], 0, 0, 0);
            acc[4][3] = __builtin_amdgcn_mfma_f32_16x16x32_bf16(fa4, fb3, acc[4][3], 0, 0, 0);
            acc[5][0] = __builtin_amdgcn_mfma_f32_16x16x32_bf16(fa5, fb0, acc[5][0], 0, 0, 0);
            acc[5][1] = __builtin_amdgcn_mfma_f32_16x16x32_bf16(fa5, fb1, acc[5][1], 0, 0, 0);
            acc[5][2] = __builtin_amdgcn_mfma_f32_16x16x32_bf16(fa5, fb2, acc[5][2], 0, 0, 0);
            acc[5][3] = __builtin_amdgcn_mfma_f32_16x16x32_bf16(fa5, fb3, acc[5][3], 0, 0, 0);
            acc[6][0] = __builtin_amdgcn_mfma_f32_16x16x32_bf16(fa6, fb0, acc[6][0], 0, 0, 0);
            acc[6][1] = __builtin_amdgcn_mfma_f32_16x16x32_bf16(fa6, fb1, acc[6][1], 0, 0, 0);
            acc[6][2] = __builtin_amdgcn_mfma_f32_16x16x32_bf16(fa6, fb2, acc[6][2], 0, 0, 0);
            acc[6][3] = __builtin_amdgcn_mfma_f32_16x16x32_bf16(fa6, fb3, acc[6][3], 0, 0, 0);
            acc[7][0] = __builtin_amdgcn_mfma_f32_16x16x32_bf16(fa7, fb0, acc[7][0], 0, 0, 0);
            acc[7][1] = __builtin_amdgcn_mfma_f32_16x16x32_bf16(fa7, fb1, acc[7][1], 0, 0, 0);
            acc[7][2] = __builtin_amdgcn_mfma_f32_16x16x32_bf16(fa7, fb2, acc[7][2], 0, 0, 0);
            acc[7][3] = __builtin_amdgcn_mfma_f32_16x16x32_bf16(fa7, fb3, acc[7][3], 0, 0, 0);
            __builtin_amdgcn_s_setprio(0);
        }

        // epilogue
        const int colb = n0 + wn * 64 + (lane & 15);
        const int rowbase = row0 + wm * 128 + ((lane >> 4) << 2);
        if (GATEUP) {
            uint16_t* Oact = (uint16_t*)OutP;
            const bool evenl = ((lane & 1) == 0);
            #pragma unroll
            for (int f = 0; f < 8; ++f)
                #pragma unroll
                for (int g = 0; g < 4; ++g) {
                    f32x4 v = acc[f][g];
                    #pragma unroll
                    for (int r = 0; r < 4; ++r) {
                        float gg = v[r];
                        float uu = __shfl_xor(gg, 1, 64);
                        int row = rowbase + f * 16 + r;
                        if (evenl && row < end) {
                            int jcol = (colb + g * 16) >> 1;
                            float sg = gg / (1.f + __expf(-gg));
                            Oact[(long)row * IDIM + jcol] = f2bf(sg * uu);
                        }
                    }
                }
        } else {
            uint16_t* Y = (uint16_t*)OutP;
            #pragma unroll
            for (int f = 0; f < 8; ++f)
                #pragma unroll
                for (int g = 0; g < 4; ++g) {
                    f32x4 v = acc[f][g];
                    #pragma unroll
                    for (int r = 0; r < 4; ++r) {
                        int row = rowbase + f * 16 + r;
                        if (row < end)
                            Y[(long)row * HDIM + colb + g * 16] = f2bf(v[r]);
                    }
                }
        }
    }
}

// ---------------- combine: out = y_shared + 2.5 * sum_k w_k * y[slot_k] ----------------
__global__ __launch_bounds__(256) void k_combine(
    float* __restrict__ out, const uint16_t* __restrict__ ybuf,
    const int* __restrict__ slot_of, const float* __restrict__ topk_w)
{
    __shared__ int sl[KTOP];
    __shared__ float sw[KTOP];
    const int t = blockIdx.x, tid = threadIdx.x;
    if (tid < KTOP) {
        sl[tid] = slot_of[t * KTOP + tid];
        sw[tid] = topk_w[t * KTOP + tid] * RSCALE;
    }
    __syncthreads();
    const int h0 = tid << 3;
    const uint16_t* sr = ybuf + (long)(TKTOT + t) * HDIM + h0;
    short8 sv = *(const short8*)sr;
    float a[8];
    #pragma unroll
    for (int j = 0; j < 8; ++j) a[j] = bf2f((uint16_t)sv[j]);
    #pragma unroll
    for (int k = 0; k < KTOP; ++k) {
        const uint16_t* yr = ybuf + (long)sl[k] * HDIM + h0;
        short8 y = *(const short8*)yr;
        float w = sw[k];
        #pragma unroll
        for (int j = 0; j < 8; ++j)
            a[j] += w * bf2f((uint16_t)y[j]);
    }
    float* orow = out + (long)t * HDIM + h0;
    float4 v0 = { a[0], a[1], a[2], a[3] };
    float4 v1 = { a[4], a[5], a[6], a[7] };
    *(float4*)(orow) = v0;
    *(float4*)(orow + 4) = v1;
}

// ---------------- launch ----------------
extern "C" void kernel_launch(void* const* d_in, const int* in_sizes, int n_in,
                              void* d_out, int out_size, void* d_ws, size_t ws_size,
                              hipStream_t stream)
{
    const float* x  = (const float*)d_in[0];
    const float* gw = (const float*)d_in[1];
    const float* eb = (const float*)d_in[2];
    const float* w1 = (const float*)d_in[3];
    const float* w2 = (const float*)d_in[4];
    const float* s1 = (const float*)d_in[5];
    const float* s2 = (const float*)d_in[6];
    float* out = (float*)d_out;
    char* ws = (char*)d_ws;

    size_t off = 0;
    auto take = [&](size_t b) { size_t r = off; off += (b + 255) & ~(size_t)255; return r; };
    const size_t oXBF = take((size_t)T_TOK * HDIM * 2);
    const size_t oACT = take((size_t)NSLOT * IDIM * 2);
    const size_t oW1T = take((size_t)(NEXP + 1) * 2048 * 2048 * 2);  // ybuf aliases
    const size_t oW2T = take((size_t)(NEXP + 1) * 2048 * 1024 * 2);
    const size_t oTKI = take((size_t)TKTOT * 4);
    const size_t oTKW = take((size_t)TKTOT * 4);
    const size_t oSLT = take((size_t)TKTOT * 4);
    const size_t oPRM = take((size_t)NSLOT * 4);
    const size_t oCTL = take(1024);     // [0..63]=counts, [64..95]=qctl
    const size_t oOFS = take(256);
    const size_t oCUR = take(256);
    const size_t oNT  = take(256);
    const size_t oIR  = take(MAXITEMS * 4);
    const size_t oIE  = take(MAXITEMS * 4);
    const size_t oIX  = take(MAXITEMS * 4);
    const size_t oIN  = take(MAXITEMS * 4);
    (void)ws_size; (void)in_sizes; (void)n_in; (void)out_size;

    uint16_t* xbf  = (uint16_t*)(ws + oXBF);
    uint16_t* act  = (uint16_t*)(ws + oACT);
    uint16_t* w1t  = (uint16_t*)(ws + oW1T);
    uint16_t* ybuf = (uint16_t*)(ws + oW1T);
    uint16_t* w2t  = (uint16_t*)(ws + oW2T);
    int*   tki  = (int*)(ws + oTKI);
    float* tkw  = (float*)(ws + oTKW);
    int*   slot = (int*)(ws + oSLT);
    int*   prm  = (int*)(ws + oPRM);
    int*   ctl  = (int*)(ws + oCTL);
    int*   ofs  = (int*)(ws + oOFS);
    int*   cur  = (int*)(ws + oCUR);
    int*   nt   = (int*)(ws + oNT);
    int*   ir0  = (int*)(ws + oIR);
    int*   iend = (int*)(ws + oIE);
    int*   ie   = (int*)(ws + oIX);
    int*   in0  = (int*)(ws + oIN);
    int*   qctl = ctl + 64;

    hipMemsetAsync(ws + oCTL, 0, 1024, stream);

    k_router<<<T_TOK / 16, 256, 0, stream>>>(x, gw, eb, tki, tkw, ctl, xbf);
    k_scan6<<<1, 64, 0, stream>>>(ctl, ofs, cur, ir0, iend, ie, in0, nt, qctl);
    k_scatter<<<(NSLOT + 255) / 256, 256, 0, stream>>>(tki, cur, prm, slot);

    k_transpose3<true ><<<dim3(32, 32, NEXP + 1), 256, 0, stream>>>(w1, s1, w1t, 2048, 2048,
        (long)2048 * 2048, (long)2048 * 2048);
    k_transpose3<false><<<dim3(32, 16, NEXP + 1), 256, 0, stream>>>(w2, s2, w2t, 1024, 2048,
        (long)1024 * 2048, (long)2048 * 1024);

    // gate_up (+silu*mul) for routed + shared -> act   (per-XCD queues q0)
    k_gemm11<true><<<dim3(256), 512, 0, stream>>>(
        xbf, w1t, act, prm, ir0, iend, ie, in0, qctl, 2048, (long)2048 * 2048);
    // down for routed + shared -> ybuf (bf16, aliases w1t; per-XCD queues q1)
    k_gemm11<false><<<dim3(256), 512, 0, stream>>>(
        act, w2t, ybuf, prm, ir0, iend, ie, in0, qctl + 16, 1024, (long)2048 * 1024);

    k_combine<<<T_TOK, 256, 0, stream>>>(out, ybuf, slot, tkw);
}

// Round 12
// 2022.384 us; speedup vs baseline: 1.1140x; 1.0448x over previous
//
#include <hip/hip_runtime.h>
#include <stdint.h>

// ---------------- problem constants ----------------
#define T_TOK 8192
#define HDIM  2048
#define IDIM  1024
#define NEXP  64
#define KTOP  8
#define TGRP  4
#define TKTOT (T_TOK*KTOP)   // 65536
#define NSLOT (TKTOT + T_TOK) // routed slots + shared rows
#define MAXITEMS 4096
#define RSCALE 2.5f

#define NRB     512            // router blocks in k_prep
#define W1TILES (65*1024)      // 65 experts x (32x32) 64x64 tiles
#define W2TILES (65*512)       // 65 experts x (32x16)

typedef __attribute__((ext_vector_type(8))) short short8;
typedef __attribute__((ext_vector_type(4))) float f32x4;

#define VMCNT(n) asm volatile("s_waitcnt vmcnt(" #n ")" ::: "memory")
#define BARRIER() asm volatile("s_barrier" ::: "memory")

__device__ __forceinline__ float bf2f(uint16_t u) {
    union { unsigned i; float f; } v; v.i = ((unsigned)u) << 16; return v.f;
}
__device__ __forceinline__ uint16_t f2bf(float f) {
    union { float f; unsigned i; } v; v.f = f;
    unsigned r = (v.i + 0x7FFFu + ((v.i >> 16) & 1u)) >> 16;
    return (uint16_t)r;
}
__device__ __forceinline__ void gload_lds16(const void* g, void* l) {
    __builtin_amdgcn_global_load_lds(
        (const __attribute__((address_space(1))) void*)g,
        (__attribute__((address_space(3))) void*)l, 16, 0, 0);
}
__device__ __forceinline__ int imin(int a, int b) { return a < b ? a : b; }

// ---------------- 64x64 transpose tile (shared helper) ----------------
template<bool INTER>
__device__ __forceinline__ void tr_tile(
    const float* __restrict__ S, uint16_t* __restrict__ D,
    int R, int C, int c0, int r0, float (*tile)[65], int tid)
{
    const int lc = (tid & 15) << 2;
    const int lr = tid >> 4;
    #pragma unroll
    for (int p = 0; p < 4; ++p) {
        int y = lr + p * 16;
        float4 v = *(const float4*)(S + (long)(r0 + y) * C + c0 + lc);
        tile[y][lc] = v.x; tile[y][lc + 1] = v.y;
        tile[y][lc + 2] = v.z; tile[y][lc + 3] = v.w;
    }
    __syncthreads();
    const int wc = tid >> 3;
    const int wx = (tid & 7) << 3;
    #pragma unroll
    for (int p = 0; p < 2; ++p) {
        int c = wc + p * 32;
        short8 v;
        #pragma unroll
        for (int j = 0; j < 8; ++j) v[j] = (short)f2bf(tile[wx + j][c]);
        int cg = c0 + c;
        int rd = INTER ? (((cg & (IDIM - 1)) << 1) + (cg >> 10)) : cg;
        *(short8*)(D + (long)rd * R + r0 + wx) = v;
    }
}

// ---------------- fused prep: router(+x->bf16) || w1/s1 || w2/s2 transposes ----
// blocks [0,NRB): router; [NRB, NRB+W1TILES): w1t; then W2TILES: w2t.
__global__ __launch_bounds__(256) void k_prep(
    const float* __restrict__ x, const float* __restrict__ gw,
    const float* __restrict__ ebias,
    const float* __restrict__ w1, const float* __restrict__ s1,
    const float* __restrict__ w2, const float* __restrict__ s2,
    uint16_t* __restrict__ w1t, uint16_t* __restrict__ w2t,
    int* __restrict__ topk_ids, float* __restrict__ topk_w,
    int* __restrict__ counts, uint16_t* __restrict__ xbf)
{
    __shared__ __align__(16) char smem[50816];
    const int tid = threadIdx.x;
    int b = blockIdx.x;

    if (b >= NRB) {
        b -= NRB;
        float (*tile)[65] = (float(*)[65])smem;
        if (b < W1TILES) {
            const int e = b >> 10, rem = b & 1023;
            const int c0 = (rem & 31) << 6, r0 = (rem >> 5) << 6;
            const float* S = (e == NEXP) ? s1 : (w1 + (long)e * 2048 * 2048);
            tr_tile<true>(S, w1t + (long)e * 2048 * 2048, 2048, 2048, c0, r0, tile, tid);
        } else {
            b -= W1TILES;
            const int e = b >> 9, rem = b & 511;
            const int c0 = (rem & 31) << 6, r0 = (rem >> 5) << 6;   // r0 < 1024
            const float* S = (e == NEXP) ? s2 : (w2 + (long)e * 1024 * 2048);
            tr_tile<false>(S, w2t + (long)e * 2048 * 1024, 1024, 2048, c0, r0, tile, tid);
        }
        return;
    }

    // ---- router role ----
    float (*xs)[132] = (float(*)[132])(smem);
    float (*wsb)[133] = (float(*)[133])(smem + 8448);
    float (*sc)[65]  = (float(*)[65])(smem + 42496);
    float (*su)[65]  = (float(*)[65])(smem + 46656);
    const int e = tid & 63;
    const int tg = tid >> 6;
    const long tblk = (long)b * 16;

    float acc0 = 0.f, acc1 = 0.f, acc2 = 0.f, acc3 = 0.f;
    for (int ch = 0; ch < 16; ++ch) {
        const int h0 = ch << 7;
        for (int i = tid; i < 512; i += 256) {
            int r = i >> 5, c4 = (i & 31) << 2;
            float4 v = *(const float4*)(x + (tblk + r) * HDIM + h0 + c4);
            *(float4*)&xs[r][c4] = v;
            uint64_t pk = (uint64_t)f2bf(v.x) | ((uint64_t)f2bf(v.y) << 16)
                        | ((uint64_t)f2bf(v.z) << 32) | ((uint64_t)f2bf(v.w) << 48);
            *(uint64_t*)(xbf + (tblk + r) * HDIM + h0 + c4) = pk;
        }
        for (int i = tid; i < 8192; i += 256) {
            int r = i >> 7, c = i & 127;
            wsb[r][c] = gw[(long)r * HDIM + h0 + c];
        }
        __syncthreads();
        #pragma unroll 8
        for (int hh = 0; hh < 128; ++hh) {
            float wv = wsb[e][hh];
            acc0 += xs[tg][hh] * wv;
            acc1 += xs[tg + 4][hh] * wv;
            acc2 += xs[tg + 8][hh] * wv;
            acc3 += xs[tg + 12][hh] * wv;
        }
        __syncthreads();
    }
    const float be = ebias[e];
    {
        float s;
        s = 1.f / (1.f + expf(-acc0)); su[tg][e] = s;      sc[tg][e] = s + be;
        s = 1.f / (1.f + expf(-acc1)); su[tg + 4][e] = s;  sc[tg + 4][e] = s + be;
        s = 1.f / (1.f + expf(-acc2)); su[tg + 8][e] = s;  sc[tg + 8][e] = s + be;
        s = 1.f / (1.f + expf(-acc3)); su[tg + 12][e] = s; sc[tg + 12][e] = s + be;
    }
    __syncthreads();
    if (tid < 16) {
        const int t = tid;
        float gs[8];
        #pragma unroll
        for (int g = 0; g < 8; ++g) {
            float m1 = -1e30f, m2 = -1e30f;
            #pragma unroll
            for (int j = 0; j < 8; ++j) {
                float v = sc[t][g * 8 + j];
                if (v > m1) { m2 = m1; m1 = v; } else if (v > m2) { m2 = v; }
            }
            gs[g] = m1 + m2;
        }
        int selmask = 0;
        #pragma unroll
        for (int it = 0; it < TGRP; ++it) {
            float best = -1e30f; int bg = 0;
            #pragma unroll
            for (int g = 0; g < 8; ++g)
                if (!((selmask >> g) & 1) && gs[g] > best) { best = gs[g]; bg = g; }
            selmask |= (1 << bg);
        }
        unsigned long long chosen = 0ull;
        int ids[KTOP]; float wv[KTOP]; float wsum = 0.f;
        #pragma unroll
        for (int it = 0; it < KTOP; ++it) {
            float best = -1e30f; int bi = 0;
            for (int ee = 0; ee < 64; ++ee) {
                if (((selmask >> (ee >> 3)) & 1) && !((chosen >> ee) & 1ull)) {
                    float v = sc[t][ee];
                    if (v > best) { best = v; bi = ee; }
                }
            }
            chosen |= (1ull << bi);
            ids[it] = bi; wv[it] = su[t][bi]; wsum += wv[it];
        }
        const float inv = 1.f / wsum;
        #pragma unroll
        for (int k = 0; k < KTOP; ++k) {
            topk_ids[(tblk + t) * KTOP + k] = ids[k];
            topk_w[(tblk + t) * KTOP + k] = wv[k] * inv;
            atomicAdd(&counts[ids[k]], 1);
        }
    }
}

// ---------------- offsets + item list (1 wave): 256-row tiles x 8 panels,
// tile-major; shared expert appended as expert 64 (rows TKTOT..TKTOT+8192).
// qctl: [0..7] q0 cur, [8..15] q0 end, [16..23] q1 cur, [24..31] q1 end
__global__ __launch_bounds__(64) void k_scan6(
    const int* __restrict__ counts, int* offsets, int* cursor,
    int* __restrict__ it_r0, int* __restrict__ it_end,
    int* __restrict__ it_e, int* __restrict__ it_n0,
    int* __restrict__ nitems, int* __restrict__ qctl)
{
    const int e = threadIdx.x;           // 0..63, one wave
    const int c = counts[e];
    int pre = c;
    #pragma unroll
    for (int d = 1; d < 64; d <<= 1) {
        int v = __shfl_up(pre, d, 64);
        if (e >= d) pre += v;
    }
    const int offE = pre - c;
    offsets[e] = offE; cursor[e] = offE;
    const int ntl = (c + 255) >> 8;
    int ipre = ntl;
    #pragma unroll
    for (int d = 1; d < 64; d <<= 1) {
        int v = __shfl_up(ipre, d, 64);
        if (e >= d) ipre += v;
    }
    const int ibase = (ipre - ntl) * 8;
    for (int t = 0; t < ntl; ++t)        // tile-major: 8 panels of a tile adjacent
        for (int p = 0; p < 8; ++p) {
            int idx = ibase + t * 8 + p;
            it_r0[idx] = offE + t * 256;
            it_end[idx] = offE + c;
            it_e[idx] = e;
            it_n0[idx] = p << 8;
        }
    const int totTl = __shfl(ipre, 63, 64);
    int NI = totTl * 8;
    // shared expert = expert 64: 32 tiles (8192 rows) x 8 panels
    if (e < 32) {
        for (int p = 0; p < 8; ++p) {
            int idx = NI + e * 8 + p;
            it_r0[idx] = TKTOT + e * 256;
            it_end[idx] = TKTOT + T_TOK;
            it_e[idx] = 64;
            it_n0[idx] = p << 8;
        }
    }
    NI += 256;
    if (e == 63) *nitems = NI;
    if (e < 8) {
        int s  = (int)(((long)e * NI) / 8);
        int en = (int)(((long)(e + 1) * NI) / 8);
        qctl[e] = s;       qctl[8 + e]  = en;
        qctl[16 + e] = s;  qctl[24 + e] = en;
    }
}

// scatter routed slots; extend perm with identity for shared rows
__global__ __launch_bounds__(256) void k_scatter(
    const int* __restrict__ topk_ids, int* cursor,
    int* __restrict__ perm_token, int* __restrict__ slot_of)
{
    int i = blockIdx.x * 256 + threadIdx.x;
    if (i < TKTOT) {
        int e = topk_ids[i];
        int pos = atomicAdd(&cursor[e], 1);
        perm_token[pos] = i >> 3;
        slot_of[i] = pos;
    } else if (i < NSLOT) {
        perm_token[i] = i - TKTOT;
    }
}

// ---------------- MFMA GEMM (v11/v9 engine verbatim: 256x256, 8 waves, 4-buf
// BK=32, canonical phases, tail-correct vmcnt, per-XCD tile-major queues).
template<bool GATEUP>
__global__ __launch_bounds__(512, 2) void k_gemm11(
    const uint16_t* __restrict__ A, const uint16_t* __restrict__ Bw,
    void* __restrict__ OutP,
    const int* __restrict__ perm_token,
    const int* __restrict__ it_r0, const int* __restrict__ it_end,
    const int* __restrict__ it_e, const int* __restrict__ it_n0,
    int* __restrict__ qcur,
    int Kd, long expStride)
{
    __shared__ char ldsb[4 * 32768];
    __shared__ int s_item;
    const int tid = threadIdx.x, lane = tid & 63, wid = tid >> 6;
    const int wm = wid >> 2, wn = wid & 3;          // 2M x 4N wave grid

    const int rchunk = lane >> 2;                                   // 0..15
    const int swzS = ((lane & 3) ^ ((lane >> 3) & 3)) << 3;         // src k-elem off
    const int swzR = ((lane >> 4) ^ ((lane >> 1) & 3)) << 4;
    const int aoff = (wm * 128 + (lane & 15)) * 64 + swzR;
    const int boff = (wn * 64 + (lane & 15)) * 64 + swzR;
    const int dstA0 = (wid * 2) * 1024;
    const int dstA1 = (wid * 2 + 1) * 1024;

    const int nKt = Kd >> 5;
    const int xcd = (int)(blockIdx.x & 7);
    const int myEnd = qcur[8 + xcd];
    int* myCur = qcur + xcd;

    for (;;) {
        __syncthreads();                  // full fence between items
        if (tid == 0) s_item = atomicAdd(myCur, 1);
        __syncthreads();
        const int it = s_item;
        if (it >= myEnd) break;
        const int row0 = it_r0[it], end = it_end[it], n0 = it_n0[it];
        const long eoff = (long)it_e[it] * expStride;

        // staging pointers: chunk c covers rows wid*32 + c*16 + rchunk
        const uint16_t *pa0, *pa1, *pb0, *pb1;
        {
            int r0l = wid * 32 + rchunk;
            int r1l = wid * 32 + 16 + rchunk;
            int ra0 = imin(row0 + r0l, end - 1);
            int ra1 = imin(row0 + r1l, end - 1);
            long ga0 = GATEUP ? (long)perm_token[ra0] : (long)ra0;
            long ga1 = GATEUP ? (long)perm_token[ra1] : (long)ra1;
            pa0 = A + ga0 * Kd + swzS;
            pa1 = A + ga1 * Kd + swzS;
            pb0 = Bw + eoff + (long)(n0 + r0l) * Kd + swzS;
            pb1 = Bw + eoff + (long)(n0 + r1l) * Kd + swzS;
        }

        f32x4 acc[8][4];
        #pragma unroll
        for (int f = 0; f < 8; ++f)
            #pragma unroll
            for (int g = 0; g < 4; ++g) { f32x4 z = {0.f,0.f,0.f,0.f}; acc[f][g] = z; }

        // prologue: stage K-tiles 0,1,2 (4 loads each per wave)
        #pragma unroll
        for (int j = 0; j < 3; ++j) {
            char* bb = ldsb + j * 32768;
            gload_lds16(pa0 + (j << 5), bb + dstA0);
            gload_lds16(pa1 + (j << 5), bb + dstA1);
            gload_lds16(pb0 + (j << 5), bb + 16384 + dstA0);
            gload_lds16(pb1 + (j << 5), bb + 16384 + dstA1);
        }

        for (int kt = 0; kt < nKt; ++kt) {
            const char* bb = ldsb + (kt & 3) * 32768;
            char* bs = ldsb + ((kt + 3) & 3) * 32768;
            const bool st = (kt + 3) < nKt;

            if (kt + 2 < nKt)      VMCNT(8);   // kt landed; kt+1,kt+2 in flight
            else if (kt + 1 < nKt) VMCNT(4);
            else                   VMCNT(0);
            BARRIER();                          // ... on every wave

            // ---- phase 0: reads fA0-3 + fB0-3, stage A(kt+3) ----
            short8 fa0 = *(const short8*)(bb + aoff);
            short8 fa1 = *(const short8*)(bb + aoff + 1024);
            short8 fa2 = *(const short8*)(bb + aoff + 2048);
            short8 fa3 = *(const short8*)(bb + aoff + 3072);
            short8 fb0 = *(const short8*)(bb + 16384 + boff);
            short8 fb1 = *(const short8*)(bb + 16384 + boff + 1024);
            short8 fb2 = *(const short8*)(bb + 16384 + boff + 2048);
            short8 fb3 = *(const short8*)(bb + 16384 + boff + 3072);
            if (st) {
                gload_lds16(pa0 + ((kt + 3) << 5), bs + dstA0);
                gload_lds16(pa1 + ((kt + 3) << 5), bs + dstA1);
            }
            BARRIER();
            __builtin_amdgcn_s_setprio(1);
            acc[0][0] = __builtin_amdgcn_mfma_f32_16x16x32_bf16(fa0, fb0, acc[0][0], 0, 0, 0);
            acc[0][1] = __builtin_amdgcn_mfma_f32_16x16x32_bf16(fa0, fb1, acc[0][1], 0, 0, 0);
            acc[0][2] = __builtin_amdgcn_mfma_f32_16x16x32_bf16(fa0, fb2, acc[0][2], 0, 0, 0);
            acc[0][3] = __builtin_amdgcn_mfma_f32_16x16x32_bf16(fa0, fb3, acc[0][3], 0, 0, 0);
            acc[1][0] = __builtin_amdgcn_mfma_f32_16x16x32_bf16(fa1, fb0, acc[1][0], 0, 0, 0);
            acc[1][1] = __builtin_amdgcn_mfma_f32_16x16x32_bf16(fa1, fb1, acc[1][1], 0, 0, 0);
            acc[1][2] = __builtin_amdgcn_mfma_f32_16x16x32_bf16(fa1, fb2, acc[1][2], 0, 0, 0);
            acc[1][3] = __builtin_amdgcn_mfma_f32_16x16x32_bf16(fa1, fb3, acc[1][3], 0, 0, 0);
            acc[2][0] = __builtin_amdgcn_mfma_f32_16x16x32_bf16(fa2, fb0, acc[2][0], 0, 0, 0);
            acc[2][1] = __builtin_amdgcn_mfma_f32_16x16x32_bf16(fa2, fb1, acc[2][1], 0, 0, 0);
            acc[2][2] = __builtin_amdgcn_mfma_f32_16x16x32_bf16(fa2, fb2, acc[2][2], 0, 0, 0);
            acc[2][3] = __builtin_amdgcn_mfma_f32_16x16x32_bf16(fa2, fb3, acc[2][3], 0, 0, 0);
            acc[3][0] = __builtin_amdgcn_mfma_f32_16x16x32_bf16(fa3, fb0, acc[3][0], 0, 0, 0);
            acc[3][1] = __builtin_amdgcn_mfma_f32_16x16x32_bf16(fa3, fb1, acc[3][1], 0, 0, 0);
            acc[3][2] = __builtin_amdgcn_mfma_f32_16x16x32_bf16(fa3, fb2, acc[3][2], 0, 0, 0);
            acc[3][3] = __builtin_amdgcn_mfma_f32_16x16x32_bf16(fa3, fb3, acc[3][3], 0, 0, 0);
            __builtin_amdgcn_s_setprio(0);

            // ---- phase 1: reads fA4-7, stage B(kt+3) ----
            short8 fa4 = *(const short8*)(bb + aoff + 4096);
            short8 fa5 = *(const short8*)(bb + aoff + 5120);
            short8 fa6 = *(const short8*)(bb + aoff + 6144);
            short8 fa7 = *(const short8*)(bb + aoff + 7168);
            if (st) {
                gload_lds16(pb0 + ((kt + 3) << 5), bs + 16384 + dstA0);
                gload_lds16(pb1 + ((kt + 3) << 5), bs + 16384 + dstA1);
            }
            BARRIER();
            __builtin_amdgcn_s_setprio(1);
            acc[4][0] = __builtin_amdgcn_mfma_f32_16x16x32_bf16(fa4, fb0, acc[4][0], 0, 0, 0);
            acc[4][1] = __builtin_amdgcn_mfma_f32_16x16x32_bf16(fa4, fb1, acc[4][1], 0, 0, 0);
            acc[4][2] = __builtin_amdgcn_mfma_f32_16x16x32_bf16(fa4, fb2, acc[4][2], 0, 0, 0);
            acc[4][3] = __builtin_amdgcn_mfma_f32_16x16x32_bf16(fa4, fb3, acc[4][3], 0, 0, 0);
            acc[5][0] = __builtin_amdgcn_mfma_f32_16x16x32_bf16(fa5, fb0, acc[5][0], 0, 0, 0);
            acc[5][1] = __builtin_amdgcn_mfma_f32_16x16x32_bf16(fa5, fb1, acc[5][1], 0, 0, 0);
            acc[5][2] = __builtin_amdgcn_mfma_f32_16x16x32_bf16(fa5, fb2, acc[5][2], 0, 0, 0);
            acc[5][3] = __builtin_amdgcn_mfma_f32_16x16x32_bf16(fa5, fb3, acc[5][3], 0, 0, 0);
            acc[6][0] = __builtin_amdgcn_mfma_f32_16x16x32_bf16(fa6, fb0, acc[6][0], 0, 0, 0);
            acc[6][1] = __builtin_amdgcn_mfma_f32_16x16x32_bf16(fa6, fb1, acc[6][1], 0, 0, 0);
            acc[6][2] = __builtin_amdgcn_mfma_f32_16x16x32_bf16(fa6, fb2, acc[6][2], 0, 0, 0);
            acc[6][3] = __builtin_amdgcn_mfma_f32_16x16x32_bf16(fa6, fb3, acc[6][3], 0, 0, 0);
            acc[7][0] = __builtin_amdgcn_mfma_f32_16x16x32_bf16(fa7, fb0, acc[7][0], 0, 0, 0);
            acc[7][1] = __builtin_amdgcn_mfma_f32_16x16x32_bf16(fa7, fb1, acc[7][1], 0, 0, 0);
            acc[7][2] = __builtin_amdgcn_mfma_f32_16x16x32_bf16(fa7, fb2, acc[7][2], 0, 0, 0);
            acc[7][3] = __builtin_amdgcn_mfma_f32_16x16x32_bf16(fa7, fb3, acc[7][3], 0, 0, 0);
            __builtin_amdgcn_s_setprio(0);
        }

        // epilogue
        const int colb = n0 + wn * 64 + (lane & 15);
        const int rowbase = row0 + wm * 128 + ((lane >> 4) << 2);
        if (GATEUP) {
            uint16_t* Oact = (uint16_t*)OutP;
            const bool evenl = ((lane & 1) == 0);
            #pragma unroll
            for (int f = 0; f < 8; ++f)
                #pragma unroll
                for (int g = 0; g < 4; ++g) {
                    f32x4 v = acc[f][g];
                    #pragma unroll
                    for (int r = 0; r < 4; ++r) {
                        float gg = v[r];
                        float uu = __shfl_xor(gg, 1, 64);
                        int row = rowbase + f * 16 + r;
                        if (evenl && row < end) {
                            int jcol = (colb + g * 16) >> 1;
                            float sg = gg / (1.f + __expf(-gg));
                            Oact[(long)row * IDIM + jcol] = f2bf(sg * uu);
                        }
                    }
                }
        } else {
            uint16_t* Y = (uint16_t*)OutP;
            #pragma unroll
            for (int f = 0; f < 8; ++f)
                #pragma unroll
                for (int g = 0; g < 4; ++g) {
                    f32x4 v = acc[f][g];
                    #pragma unroll
                    for (int r = 0; r < 4; ++r) {
                        int row = rowbase + f * 16 + r;
                        if (row < end)
                            Y[(long)row * HDIM + colb + g * 16] = f2bf(v[r]);
                    }
                }
        }
    }
}

// ---------------- combine: out = y_shared + 2.5 * sum_k w_k * y[slot_k] ----------------
__global__ __launch_bounds__(256) void k_combine(
    float* __restrict__ out, const uint16_t* __restrict__ ybuf,
    const int* __restrict__ slot_of, const float* __restrict__ topk_w)
{
    __shared__ int sl[KTOP];
    __shared__ float sw[KTOP];
    const int t = blockIdx.x, tid = threadIdx.x;
    if (tid < KTOP) {
        sl[tid] = slot_of[t * KTOP + tid];
        sw[tid] = topk_w[t * KTOP + tid] * RSCALE;
    }
    __syncthreads();
    const int h0 = tid << 3;
    const uint16_t* sr = ybuf + (long)(TKTOT + t) * HDIM + h0;
    short8 sv = *(const short8*)sr;
    float a[8];
    #pragma unroll
    for (int j = 0; j < 8; ++j) a[j] = bf2f((uint16_t)sv[j]);
    #pragma unroll
    for (int k = 0; k < KTOP; ++k) {
        const uint16_t* yr = ybuf + (long)sl[k] * HDIM + h0;
        short8 y = *(const short8*)yr;
        float w = sw[k];
        #pragma unroll
        for (int j = 0; j < 8; ++j)
            a[j] += w * bf2f((uint16_t)y[j]);
    }
    float* orow = out + (long)t * HDIM + h0;
    float4 v0 = { a[0], a[1], a[2], a[3] };
    float4 v1 = { a[4], a[5], a[6], a[7] };
    *(float4*)(orow) = v0;
    *(float4*)(orow + 4) = v1;
}

// ---------------- launch ----------------
extern "C" void kernel_launch(void* const* d_in, const int* in_sizes, int n_in,
                              void* d_out, int out_size, void* d_ws, size_t ws_size,
                              hipStream_t stream)
{
    const float* x  = (const float*)d_in[0];
    const float* gw = (const float*)d_in[1];
    const float* eb = (const float*)d_in[2];
    const float* w1 = (const float*)d_in[3];
    const float* w2 = (const float*)d_in[4];
    const float* s1 = (const float*)d_in[5];
    const float* s2 = (const float*)d_in[6];
    float* out = (float*)d_out;
    char* ws = (char*)d_ws;

    size_t off = 0;
    auto take = [&](size_t b) { size_t r = off; off += (b + 255) & ~(size_t)255; return r; };
    const size_t oXBF = take((size_t)T_TOK * HDIM * 2);
    const size_t oACT = take((size_t)NSLOT * IDIM * 2);
    const size_t oW1T = take((size_t)(NEXP + 1) * 2048 * 2048 * 2);  // ybuf aliases
    const size_t oW2T = take((size_t)(NEXP + 1) * 2048 * 1024 * 2);
    const size_t oTKI = take((size_t)TKTOT * 4);
    const size_t oTKW = take((size_t)TKTOT * 4);
    const size_t oSLT = take((size_t)TKTOT * 4);
    const size_t oPRM = take((size_t)NSLOT * 4);
    const size_t oCTL = take(1024);     // [0..63]=counts, [64..95]=qctl
    const size_t oOFS = take(256);
    const size_t oCUR = take(256);
    const size_t oNT  = take(256);
    const size_t oIR  = take(MAXITEMS * 4);
    const size_t oIE  = take(MAXITEMS * 4);
    const size_t oIX  = take(MAXITEMS * 4);
    const size_t oIN  = take(MAXITEMS * 4);
    (void)ws_size; (void)in_sizes; (void)n_in; (void)out_size;

    uint16_t* xbf  = (uint16_t*)(ws + oXBF);
    uint16_t* act  = (uint16_t*)(ws + oACT);
    uint16_t* w1t  = (uint16_t*)(ws + oW1T);
    uint16_t* ybuf = (uint16_t*)(ws + oW1T);
    uint16_t* w2t  = (uint16_t*)(ws + oW2T);
    int*   tki  = (int*)(ws + oTKI);
    float* tkw  = (float*)(ws + oTKW);
    int*   slot = (int*)(ws + oSLT);
    int*   prm  = (int*)(ws + oPRM);
    int*   ctl  = (int*)(ws + oCTL);
    int*   ofs  = (int*)(ws + oOFS);
    int*   cur  = (int*)(ws + oCUR);
    int*   nt   = (int*)(ws + oNT);
    int*   ir0  = (int*)(ws + oIR);
    int*   iend = (int*)(ws + oIE);
    int*   ie   = (int*)(ws + oIX);
    int*   in0  = (int*)(ws + oIN);
    int*   qctl = ctl + 64;

    hipMemsetAsync(ws + oCTL, 0, 1024, stream);

    // fused prep: router (+x->bf16) overlapped with all weight transposes
    k_prep<<<dim3(NRB + W1TILES + W2TILES), 256, 0, stream>>>(
        x, gw, eb, w1, s1, w2, s2, w1t, w2t, tki, tkw, ctl, xbf);

    k_scan6<<<1, 64, 0, stream>>>(ctl, ofs, cur, ir0, iend, ie, in0, nt, qctl);
    k_scatter<<<(NSLOT + 255) / 256, 256, 0, stream>>>(tki, cur, prm, slot);

    // gate_up (+silu*mul) for routed + shared -> act   (per-XCD queues q0)
    k_gemm11<true><<<dim3(256), 512, 0, stream>>>(
        xbf, w1t, act, prm, ir0, iend, ie, in0, qctl, 2048, (long)2048 * 2048);
    // down for routed + shared -> ybuf (bf16, aliases w1t; per-XCD queues q1)
    k_gemm11<false><<<dim3(256), 512, 0, stream>>>(
        act, w2t, ybuf, prm, ir0, iend, ie, in0, qctl + 16, 1024, (long)2048 * 1024);

    k_combine<<<T_TOK, 256, 0, stream>>>(out, ybuf, slot, tkw);
}